// Round 10
// baseline (293.374 us; speedup 1.0000x reference)
//
#include <hip/hip_runtime.h>
#include <hip/hip_cooperative_groups.h>

namespace cg = cooperative_groups;

// SplineDisp: field[v] = ma @ (g(v) + cubic_bspline_pull(coeff, g(v))),
// g(v) = fa @ v, fa = inv(affine)@fix_affine, ma = inv(mov_affine)@affine.
// Fixed size: coeff [80,80,80,3] f32, out [160,160,160,3] f32.
// R10: ONE cooperative kernel containing R9's three proven phases
// (z / y / x register-window passes, bf16x3 intermediates in d_ws),
// separated by grid.sync() — removes the setup dispatch and all
// inter-kernel launch gaps. Matrices computed per-block in LDS.
// Fallback to the R9 multi-launch path if cooperative launch fails.

#define CX 80
#define FD 160

__device__ __host__ inline void inv4_f(const float* m, float* inv) {
    inv[0]  =  m[5]*m[10]*m[15] - m[5]*m[11]*m[14] - m[9]*m[6]*m[15] + m[9]*m[7]*m[14] + m[13]*m[6]*m[11] - m[13]*m[7]*m[10];
    inv[4]  = -m[4]*m[10]*m[15] + m[4]*m[11]*m[14] + m[8]*m[6]*m[15] - m[8]*m[7]*m[14] - m[12]*m[6]*m[11] + m[12]*m[7]*m[10];
    inv[8]  =  m[4]*m[9]*m[15]  - m[4]*m[11]*m[13] - m[8]*m[5]*m[15] + m[8]*m[7]*m[13] + m[12]*m[5]*m[11] - m[12]*m[7]*m[9];
    inv[12] = -m[4]*m[9]*m[14]  + m[4]*m[10]*m[13] + m[8]*m[5]*m[14] - m[8]*m[6]*m[13] - m[12]*m[5]*m[10] + m[12]*m[6]*m[9];
    inv[1]  = -m[1]*m[10]*m[15] + m[1]*m[11]*m[14] + m[9]*m[2]*m[15] - m[9]*m[3]*m[14] - m[13]*m[2]*m[11] + m[13]*m[3]*m[10];
    inv[5]  =  m[0]*m[10]*m[15] - m[0]*m[11]*m[14] - m[8]*m[2]*m[15] + m[8]*m[3]*m[14] + m[12]*m[2]*m[11] - m[12]*m[3]*m[10];
    inv[9]  = -m[0]*m[9]*m[15]  + m[0]*m[11]*m[13] + m[8]*m[1]*m[15] - m[8]*m[3]*m[13] - m[12]*m[1]*m[11] + m[12]*m[3]*m[9];
    inv[13] =  m[0]*m[9]*m[14]  - m[0]*m[10]*m[13] - m[8]*m[1]*m[14] + m[8]*m[2]*m[13] + m[12]*m[1]*m[10] - m[12]*m[2]*m[9];
    inv[2]  =  m[1]*m[6]*m[15]  - m[1]*m[7]*m[14]  - m[5]*m[2]*m[15] + m[5]*m[3]*m[14] + m[13]*m[2]*m[7]  - m[13]*m[3]*m[6];
    inv[6]  = -m[0]*m[6]*m[15]  + m[0]*m[7]*m[14]  + m[4]*m[2]*m[15] - m[4]*m[3]*m[14] - m[12]*m[2]*m[7]  + m[12]*m[3]*m[6];
    inv[10] =  m[0]*m[5]*m[15]  - m[0]*m[7]*m[13]  - m[4]*m[1]*m[15] + m[4]*m[3]*m[13] + m[12]*m[1]*m[7]  - m[12]*m[3]*m[5];
    inv[14] = -m[0]*m[5]*m[14]  + m[0]*m[6]*m[13]  + m[4]*m[1]*m[14] - m[4]*m[2]*m[13] - m[12]*m[1]*m[6]  + m[12]*m[2]*m[5];
    inv[3]  = -m[1]*m[6]*m[11]  + m[1]*m[7]*m[10]  + m[5]*m[2]*m[11] - m[5]*m[3]*m[10] - m[9]*m[2]*m[7]   + m[9]*m[3]*m[6];
    inv[7]  =  m[0]*m[6]*m[11]  - m[0]*m[7]*m[10]  - m[4]*m[2]*m[11] + m[4]*m[3]*m[10] + m[8]*m[2]*m[7]   - m[8]*m[3]*m[6];
    inv[11] = -m[0]*m[5]*m[11]  + m[0]*m[7]*m[9]   + m[4]*m[1]*m[11] - m[4]*m[3]*m[9]  - m[8]*m[1]*m[7]   + m[8]*m[3]*m[5];
    inv[15] =  m[0]*m[5]*m[10]  - m[0]*m[6]*m[9]   - m[4]*m[1]*m[10] + m[4]*m[2]*m[9]  + m[8]*m[1]*m[6]   - m[8]*m[2]*m[5];
    float det = m[0]*inv[0] + m[1]*inv[4] + m[2]*inv[8] + m[3]*inv[12];
    float rdet = 1.0f / det;
    for (int i = 0; i < 16; ++i) inv[i] *= rdet;
}

__device__ inline void compute_M(const float* affine, const float* fix_aff,
                                 const float* mov_aff, float* M) {
    float invA[16], invM[16];
    inv4_f(affine, invA);
    inv4_f(mov_aff, invM);
    for (int r = 0; r < 4; ++r)
        for (int c = 0; c < 4; ++c) {
            float s1 = 0.f, s2 = 0.f;
            for (int k = 0; k < 4; ++k) {
                s1 += invA[r*4+k] * fix_aff[k*4+c];
                s2 += invM[r*4+k] * affine[k*4+c];
            }
            M[r*4+c] = s1;
            M[16 + r*4+c] = s2;
        }
    float od = fabsf(M[1]) + fabsf(M[2]) + fabsf(M[4]) + fabsf(M[6]) + fabsf(M[8]) + fabsf(M[9]);
    int ok = (od < 1e-20f)
          && (M[0]  > 0.f) && (M[0]  <= 1.f)
          && (M[5]  > 0.f) && (M[5]  <= 1.f)
          && (M[10] > 0.f) && (M[10] <= 1.f);
    M[32] = ok ? 1.f : 0.f;
}

__device__ inline void bspline_w(float t, float w[4]) {
    float t2 = t * t;
    float t3 = t2 * t;
    const float s = 1.0f / 6.0f;
    w[0] = (1.f - 3.f*t + 3.f*t2 - t3) * s;
    w[1] = (4.f - 6.f*t2 + 3.f*t3) * s;
    w[2] = (1.f + 3.f*t + 3.f*t2 - 3.f*t3) * s;
    w[3] = t3 * s;
}

__device__ inline int wrap80(int v) {
    int r = v % CX;
    return (r < 0) ? r + CX : r;
}

__device__ inline unsigned short pk(float f) {
    unsigned u = __float_as_uint(f);
    u = (u + 0x7FFFu + ((u >> 16) & 1u)) >> 16;
    return (unsigned short)u;
}
__device__ inline float upk(unsigned short h) {
    return __uint_as_float((unsigned)h << 16);
}

// ---------------- phase bodies (R9-proven) ----------------

__device__ inline void body_z(int item, const float* __restrict__ coeff,
                              const float* M, ushort4* __restrict__ T1) {
    int k = item % FD;
    int r = item / FD;          // r = x*80 + y
    float gz = M[10] * (float)k + M[11];
    float fz = floorf(gz);
    float wz[4];
    bspline_w(gz - fz, wz);
    int bz = wrap80((int)fz - 1);
    const float* base = coeff + (size_t)r * (CX * 3);
    float a0 = 0.f, a1 = 0.f, a2 = 0.f;
#pragma unroll
    for (int c = 0; c < 4; ++c) {
        int zc = bz + c; if (zc >= CX) zc -= CX;
        const float* p = base + zc * 3;
        float w = wz[c];
        a0 = fmaf(w, p[0], a0);
        a1 = fmaf(w, p[1], a1);
        a2 = fmaf(w, p[2], a2);
    }
    ushort4 v; v.x = pk(a0); v.y = pk(a1); v.z = pk(a2); v.w = 0;
    T1[item] = v;
}

__device__ inline void body_y(int item, const float* M,
                              const ushort4* __restrict__ T1,
                              ushort4* __restrict__ T2) {
    int k = item % FD;
    int r = item / FD;
    int jg = r % 20;
    int x = r / 20;
    int j0 = jg * 8;

    const float m5 = M[5], m7 = M[7];
    const ushort4* Tx = T1 + (size_t)x * CX * FD + k;

    float gy = m5 * (float)j0 + m7;
    float fy = floorf(gy);
    int nb = (int)fy - 1;
    float wy[4];
    bspline_w(gy - fy, wy);

    ushort4 w0, w1, w2, w3;
    {
        int y0 = wrap80(nb);
        int y1 = y0 + 1; if (y1 >= CX) y1 -= CX;
        int y2 = y1 + 1; if (y2 >= CX) y2 -= CX;
        int y3 = y2 + 1; if (y3 >= CX) y3 -= CX;
        w0 = Tx[(size_t)y0 * FD];
        w1 = Tx[(size_t)y1 * FD];
        w2 = Tx[(size_t)y2 * FD];
        w3 = Tx[(size_t)y3 * FD];
    }

    ushort4* To = T2 + ((size_t)(x * FD + j0)) * FD + k;
#pragma unroll
    for (int d = 0; d < 8; ++d) {
        if (d > 0) {
            int j = j0 + d;
            gy = m5 * (float)j + m7;
            fy = floorf(gy);
            int b2 = (int)fy - 1;
            if (b2 != nb) {
                w0 = w1; w1 = w2; w2 = w3;
                w3 = Tx[(size_t)wrap80(b2 + 3) * FD];
                nb = b2;
            }
            bspline_w(gy - fy, wy);
        }
        float a0 = wy[0]*upk(w0.x) + wy[1]*upk(w1.x) + wy[2]*upk(w2.x) + wy[3]*upk(w3.x);
        float a1 = wy[0]*upk(w0.y) + wy[1]*upk(w1.y) + wy[2]*upk(w2.y) + wy[3]*upk(w3.y);
        float a2 = wy[0]*upk(w0.z) + wy[1]*upk(w1.z) + wy[2]*upk(w2.z) + wy[3]*upk(w3.z);
        ushort4 v; v.x = pk(a0); v.y = pk(a1); v.z = pk(a2); v.w = 0;
        To[(size_t)d * FD] = v;
    }
}

__device__ inline void body_x(int item, const float* __restrict__ coeff,
                              const float* M, const ushort4* __restrict__ T2,
                              float* __restrict__ out, int separable) {
    int k = item % FD;
    int r = item / FD;
    int j = r % FD;
    int ig = r / FD;
    int i0 = ig * 8;

    if (separable) {
        const float m0 = M[0], m3 = M[3];
        const float gy = M[5] * (float)j + M[7];
        const float gz = M[10] * (float)k + M[11];
        const ushort4* Tjk = T2 + (size_t)j * FD + k;

        float gx = m0 * (float)i0 + m3;
        float fx = floorf(gx);
        int nb = (int)fx - 1;
        float wx[4];
        bspline_w(gx - fx, wx);

        ushort4 w0, w1, w2, w3;
        {
            const size_t S = (size_t)FD * FD;
            int x0 = wrap80(nb);
            int x1 = x0 + 1; if (x1 >= CX) x1 -= CX;
            int x2 = x1 + 1; if (x2 >= CX) x2 -= CX;
            int x3 = x2 + 1; if (x3 >= CX) x3 -= CX;
            w0 = Tjk[(size_t)x0 * S];
            w1 = Tjk[(size_t)x1 * S];
            w2 = Tjk[(size_t)x2 * S];
            w3 = Tjk[(size_t)x3 * S];
        }

        float* po = out + (((size_t)(i0 * FD + j)) * FD + k) * 3;
#pragma unroll
        for (int d = 0; d < 8; ++d) {
            float gxd = gx;
            if (d > 0) {
                int i = i0 + d;
                gxd = m0 * (float)i + m3;
                float fx2 = floorf(gxd);
                int b2 = (int)fx2 - 1;
                if (b2 != nb) {
                    w0 = w1; w1 = w2; w2 = w3;
                    w3 = Tjk[(size_t)wrap80(b2 + 3) * FD * FD];
                    nb = b2;
                }
                bspline_w(gxd - fx2, wx);
            }
            float a0 = wx[0]*upk(w0.x) + wx[1]*upk(w1.x) + wx[2]*upk(w2.x) + wx[3]*upk(w3.x);
            float a1 = wx[0]*upk(w0.y) + wx[1]*upk(w1.y) + wx[2]*upk(w2.y) + wx[3]*upk(w3.y);
            float a2 = wx[0]*upk(w0.z) + wx[1]*upk(w1.z) + wx[2]*upk(w2.z) + wx[3]*upk(w3.z);
            float ux = gxd + a0, uy = gy + a1, uz = gz + a2;
            po[0] = M[16]*ux + M[17]*uy + M[18]*uz + M[19];
            po[1] = M[20]*ux + M[21]*uy + M[22]*uz + M[23];
            po[2] = M[24]*ux + M[25]*uy + M[26]*uz + M[27];
            po += (size_t)FD * FD * 3;
        }
    } else {
        for (int d = 0; d < 8; ++d) {
            int i = i0 + d;
            float fi = (float)i, fj = (float)j, fk = (float)k;
            float gx = M[0]*fi + M[1]*fj + M[2]*fk  + M[3];
            float gy = M[4]*fi + M[5]*fj + M[6]*fk  + M[7];
            float gz = M[8]*fi + M[9]*fj + M[10]*fk + M[11];
            float fx = floorf(gx), fy = floorf(gy), fz = floorf(gz);
            float wx[4], wy[4], wz[4];
            bspline_w(gx - fx, wx);
            bspline_w(gy - fy, wy);
            bspline_w(gz - fz, wz);
            int bxw = wrap80((int)fx - 1);
            int byw = wrap80((int)fy - 1);
            int bzw = wrap80((int)fz - 1);
            int ox[4], oy[4], oz[4];
            for (int a = 0; a < 4; ++a) {
                int xa = bxw + a; if (xa >= CX) xa -= CX;
                int ya = byw + a; if (ya >= CX) ya -= CX;
                int za = bzw + a; if (za >= CX) za -= CX;
                ox[a] = xa * (CX*CX*3);
                oy[a] = ya * (CX*3);
                oz[a] = za * 3;
            }
            float a0 = 0.f, a1 = 0.f, a2 = 0.f;
            for (int a = 0; a < 4; ++a)
                for (int b = 0; b < 4; ++b)
                    for (int c = 0; c < 4; ++c) {
                        float w = wx[a] * wy[b] * wz[c];
                        const float* p = coeff + (ox[a] + oy[b] + oz[c]);
                        a0 = fmaf(w, p[0], a0);
                        a1 = fmaf(w, p[1], a1);
                        a2 = fmaf(w, p[2], a2);
                    }
            float ux = gx + a0, uy = gy + a1, uz = gz + a2;
            size_t o = ((size_t)(i * FD + j) * FD + k) * 3;
            out[o + 0] = M[16]*ux + M[17]*uy + M[18]*uz + M[19];
            out[o + 1] = M[20]*ux + M[21]*uy + M[22]*uz + M[23];
            out[o + 2] = M[24]*ux + M[25]*uy + M[26]*uz + M[27];
        }
    }
}

// ---------------- cooperative fused kernel ----------------

#define NBLK 1024

__global__ __launch_bounds__(256, 4) void spline_coop(const float* __restrict__ coeff,
                                                      const float* __restrict__ affine,
                                                      const float* __restrict__ fix_aff,
                                                      const float* __restrict__ mov_aff,
                                                      ushort4* __restrict__ T1,
                                                      ushort4* __restrict__ T2,
                                                      float* __restrict__ out) {
    __shared__ float sM[33];
    if (threadIdx.x == 0) compute_M(affine, fix_aff, mov_aff, sM);
    __syncthreads();

    float M[33];
#pragma unroll
    for (int q = 0; q < 33; ++q) M[q] = sM[q];
    const int separable = (M[32] != 0.f);

    cg::grid_group grid = cg::this_grid();
    const int gtid  = blockIdx.x * 256 + threadIdx.x;
    const int gsize = NBLK * 256;                    // 262,144

    if (separable) {
        // phase z: 1,024,000 items
        for (int item = gtid; item < CX*CX*FD; item += gsize)
            body_z(item, coeff, M, T1);
        grid.sync();
        // phase y: 256,000 items
        for (int item = gtid; item < CX*20*FD; item += gsize)
            body_y(item, M, T1, T2);
        grid.sync();
    } else {
        grid.sync();
        grid.sync();
    }
    // phase x: 512,000 items
    for (int item = gtid; item < 20*FD*FD; item += gsize)
        body_x(item, coeff, M, T2, out, separable);
}

// ---------------- non-cooperative fallback (R9 path) ----------------

__global__ void setup_mats(const float* __restrict__ affine,
                           const float* __restrict__ fix_aff,
                           const float* __restrict__ mov_aff,
                           float* __restrict__ M) {
    if (threadIdx.x != 0 || blockIdx.x != 0) return;
    compute_M(affine, fix_aff, mov_aff, M);
}

__global__ __launch_bounds__(256) void pass_z_k(const float* __restrict__ coeff,
                                                const float* __restrict__ M,
                                                ushort4* __restrict__ T1) {
    if (M[32] == 0.f) return;
    int tid = blockIdx.x * 256 + threadIdx.x;
    body_z(tid, coeff, M, T1);
}

__global__ __launch_bounds__(256) void pass_y_k(const float* __restrict__ M,
                                                const ushort4* __restrict__ T1,
                                                ushort4* __restrict__ T2) {
    if (M[32] == 0.f) return;
    int tid = blockIdx.x * 256 + threadIdx.x;
    body_y(tid, M, T1, T2);
}

__global__ __launch_bounds__(256) void pass_x_k(const float* __restrict__ coeff,
                                                const float* __restrict__ M,
                                                const ushort4* __restrict__ T2,
                                                float* __restrict__ out) {
    int tid = blockIdx.x * 256 + threadIdx.x;
    body_x(tid, coeff, M, T2, out, M[32] != 0.f);
}

__global__ __launch_bounds__(256) void spline_direct(const float* __restrict__ coeff,
                                                     const float* __restrict__ M,
                                                     float* __restrict__ out) {
    int tid = blockIdx.x * 256 + threadIdx.x;
    int k = tid % FD;
    int r = tid / FD;
    int j = r % FD;
    int i = r / FD;
    float fi = (float)i, fj = (float)j, fk = (float)k;
    float gx = M[0]*fi + M[1]*fj + M[2]*fk  + M[3];
    float gy = M[4]*fi + M[5]*fj + M[6]*fk  + M[7];
    float gz = M[8]*fi + M[9]*fj + M[10]*fk + M[11];
    float fx = floorf(gx), fy = floorf(gy), fz = floorf(gz);
    float wx[4], wy[4], wz[4];
    bspline_w(gx - fx, wx);
    bspline_w(gy - fy, wy);
    bspline_w(gz - fz, wz);
    int bxw = wrap80((int)fx - 1);
    int byw = wrap80((int)fy - 1);
    int bzw = wrap80((int)fz - 1);
    int ox[4], oy[4], oz[4];
#pragma unroll
    for (int a = 0; a < 4; ++a) {
        int xa = bxw + a; if (xa >= CX) xa -= CX;
        int ya = byw + a; if (ya >= CX) ya -= CX;
        int za = bzw + a; if (za >= CX) za -= CX;
        ox[a] = xa * (CX*CX*3);
        oy[a] = ya * (CX*3);
        oz[a] = za * 3;
    }
    float a0 = 0.f, a1 = 0.f, a2 = 0.f;
#pragma unroll
    for (int a = 0; a < 4; ++a)
#pragma unroll
        for (int b = 0; b < 4; ++b)
#pragma unroll
            for (int c = 0; c < 4; ++c) {
                float w = wx[a] * wy[b] * wz[c];
                const float* p = coeff + (ox[a] + oy[b] + oz[c]);
                a0 = fmaf(w, p[0], a0);
                a1 = fmaf(w, p[1], a1);
                a2 = fmaf(w, p[2], a2);
            }
    float ux = gx + a0, uy = gy + a1, uz = gz + a2;
    out[tid*3 + 0] = M[16]*ux + M[17]*uy + M[18]*uz + M[19];
    out[tid*3 + 1] = M[20]*ux + M[21]*uy + M[22]*uz + M[23];
    out[tid*3 + 2] = M[24]*ux + M[25]*uy + M[26]*uz + M[27];
}

extern "C" void kernel_launch(void* const* d_in, const int* in_sizes, int n_in,
                              void* d_out, int out_size, void* d_ws, size_t ws_size,
                              hipStream_t stream) {
    const float* coeff   = (const float*)d_in[0];
    const float* affine  = (const float*)d_in[1];
    const float* fix_aff = (const float*)d_in[2];
    const float* mov_aff = (const float*)d_in[3];
    float* M    = (float*)d_ws;
    char*  ws   = (char*)d_ws;
    ushort4* T1 = (ushort4*)(ws + 256);                           // 8,192,000 B
    ushort4* T2 = (ushort4*)(ws + 256 + (size_t)CX*CX*FD*8);      // 16,384,000 B
    float* out  = (float*)d_out;

    const size_t need = 256 + (size_t)CX*CX*FD*8 + (size_t)CX*FD*FD*8;

    if (ws_size >= need) {
        void* args[] = { (void*)&coeff, (void*)&affine, (void*)&fix_aff,
                         (void*)&mov_aff, (void*)&T1, (void*)&T2, (void*)&out };
        hipError_t err = hipLaunchCooperativeKernel((void*)spline_coop,
                                                    dim3(NBLK), dim3(256),
                                                    args, 0, stream);
        if (err == hipSuccess) return;
        // fall back to the proven R9 multi-launch path
        setup_mats<<<1, 64, 0, stream>>>(affine, fix_aff, mov_aff, M);
        pass_z_k<<<(CX*CX*FD)/256, 256, 0, stream>>>(coeff, M, T1);
        pass_y_k<<<(CX*20*FD)/256, 256, 0, stream>>>(M, T1, T2);
        pass_x_k<<<(20*FD*FD)/256, 256, 0, stream>>>(coeff, M, T2, out);
    } else {
        setup_mats<<<1, 64, 0, stream>>>(affine, fix_aff, mov_aff, M);
        spline_direct<<<(FD*FD*FD)/256, 256, 0, stream>>>(coeff, M, out);
    }
}

// Round 11
// 99.972 us; speedup vs baseline: 2.9346x; 2.9346x over previous
//
#include <hip/hip_runtime.h>

// SplineDisp: field[v] = ma @ (g(v) + cubic_bspline_pull(coeff, g(v))),
// g(v) = fa @ v, fa = inv(affine)@fix_affine, ma = inv(mov_affine)@affine.
// Fixed size: coeff [80,80,80,3] f32, out [160,160,160,3] f32.
// R11: R9 three-pass structure (register sliding windows, bf16x3
// intermediates) with the setup dispatch REMOVED: every pass computes the
// fa/ma/flag block per-workgroup (thread 0 -> LDS broadcast). 3 dispatches.
// (R10's cooperative grid.sync cost ~100us/barrier on 8 XCDs — reverted.)

#define CX 80
#define FD 160

__device__ inline void inv4_f(const float* m, float* inv) {
    inv[0]  =  m[5]*m[10]*m[15] - m[5]*m[11]*m[14] - m[9]*m[6]*m[15] + m[9]*m[7]*m[14] + m[13]*m[6]*m[11] - m[13]*m[7]*m[10];
    inv[4]  = -m[4]*m[10]*m[15] + m[4]*m[11]*m[14] + m[8]*m[6]*m[15] - m[8]*m[7]*m[14] - m[12]*m[6]*m[11] + m[12]*m[7]*m[10];
    inv[8]  =  m[4]*m[9]*m[15]  - m[4]*m[11]*m[13] - m[8]*m[5]*m[15] + m[8]*m[7]*m[13] + m[12]*m[5]*m[11] - m[12]*m[7]*m[9];
    inv[12] = -m[4]*m[9]*m[14]  + m[4]*m[10]*m[13] + m[8]*m[5]*m[14] - m[8]*m[6]*m[13] - m[12]*m[5]*m[10] + m[12]*m[6]*m[9];
    inv[1]  = -m[1]*m[10]*m[15] + m[1]*m[11]*m[14] + m[9]*m[2]*m[15] - m[9]*m[3]*m[14] - m[13]*m[2]*m[11] + m[13]*m[3]*m[10];
    inv[5]  =  m[0]*m[10]*m[15] - m[0]*m[11]*m[14] - m[8]*m[2]*m[15] + m[8]*m[3]*m[14] + m[12]*m[2]*m[11] - m[12]*m[3]*m[10];
    inv[9]  = -m[0]*m[9]*m[15]  + m[0]*m[11]*m[13] + m[8]*m[1]*m[15] - m[8]*m[3]*m[13] - m[12]*m[1]*m[11] + m[12]*m[3]*m[9];
    inv[13] =  m[0]*m[9]*m[14]  - m[0]*m[10]*m[13] - m[8]*m[1]*m[14] + m[8]*m[2]*m[13] + m[12]*m[1]*m[10] - m[12]*m[2]*m[9];
    inv[2]  =  m[1]*m[6]*m[15]  - m[1]*m[7]*m[14]  - m[5]*m[2]*m[15] + m[5]*m[3]*m[14] + m[13]*m[2]*m[7]  - m[13]*m[3]*m[6];
    inv[6]  = -m[0]*m[6]*m[15]  + m[0]*m[7]*m[14]  + m[4]*m[2]*m[15] - m[4]*m[3]*m[14] - m[12]*m[2]*m[7]  + m[12]*m[3]*m[6];
    inv[10] =  m[0]*m[5]*m[15]  - m[0]*m[7]*m[13]  - m[4]*m[1]*m[15] + m[4]*m[3]*m[13] + m[12]*m[1]*m[7]  - m[12]*m[3]*m[5];
    inv[14] = -m[0]*m[5]*m[14]  + m[0]*m[6]*m[13]  + m[4]*m[1]*m[14] - m[4]*m[2]*m[13] - m[12]*m[1]*m[6]  + m[12]*m[2]*m[5];
    inv[3]  = -m[1]*m[6]*m[11]  + m[1]*m[7]*m[10]  + m[5]*m[2]*m[11] - m[5]*m[3]*m[10] - m[9]*m[2]*m[7]   + m[9]*m[3]*m[6];
    inv[7]  =  m[0]*m[6]*m[11]  - m[0]*m[7]*m[10]  - m[4]*m[2]*m[11] + m[4]*m[3]*m[10] + m[8]*m[2]*m[7]   - m[8]*m[3]*m[6];
    inv[11] = -m[0]*m[5]*m[11]  + m[0]*m[7]*m[9]   + m[4]*m[1]*m[11] - m[4]*m[3]*m[9]  - m[8]*m[1]*m[7]   + m[8]*m[3]*m[5];
    inv[15] =  m[0]*m[5]*m[10]  - m[0]*m[6]*m[9]   - m[4]*m[1]*m[10] + m[4]*m[2]*m[9]  + m[8]*m[1]*m[6]   - m[8]*m[2]*m[5];
    float det = m[0]*inv[0] + m[1]*inv[4] + m[2]*inv[8] + m[3]*inv[12];
    float rdet = 1.0f / det;
    for (int i = 0; i < 16; ++i) inv[i] *= rdet;
}

__device__ inline void compute_M(const float* affine, const float* fix_aff,
                                 const float* mov_aff, float* M) {
    float invA[16], invM[16];
    inv4_f(affine, invA);
    inv4_f(mov_aff, invM);
    for (int r = 0; r < 4; ++r)
        for (int c = 0; c < 4; ++c) {
            float s1 = 0.f, s2 = 0.f;
            for (int k = 0; k < 4; ++k) {
                s1 += invA[r*4+k] * fix_aff[k*4+c];
                s2 += invM[r*4+k] * affine[k*4+c];
            }
            M[r*4+c] = s1;
            M[16 + r*4+c] = s2;
        }
    float od = fabsf(M[1]) + fabsf(M[2]) + fabsf(M[4]) + fabsf(M[6]) + fabsf(M[8]) + fabsf(M[9]);
    int ok = (od < 1e-20f)
          && (M[0]  > 0.f) && (M[0]  <= 1.f)
          && (M[5]  > 0.f) && (M[5]  <= 1.f)
          && (M[10] > 0.f) && (M[10] <= 1.f);
    M[32] = ok ? 1.f : 0.f;
}

// per-block: thread 0 computes M into LDS, all threads copy to registers
#define BLOCK_M(Mreg)                                                   \
    __shared__ float sM_[33];                                           \
    if (threadIdx.x == 0) compute_M(affine, fix_aff, mov_aff, sM_);     \
    __syncthreads();                                                    \
    float Mreg[33];                                                     \
    _Pragma("unroll")                                                   \
    for (int q_ = 0; q_ < 33; ++q_) Mreg[q_] = sM_[q_];

__device__ inline void bspline_w(float t, float w[4]) {
    float t2 = t * t;
    float t3 = t2 * t;
    const float s = 1.0f / 6.0f;
    w[0] = (1.f - 3.f*t + 3.f*t2 - t3) * s;
    w[1] = (4.f - 6.f*t2 + 3.f*t3) * s;
    w[2] = (1.f + 3.f*t + 3.f*t2 - 3.f*t3) * s;
    w[3] = t3 * s;
}

__device__ inline int wrap80(int v) {
    int r = v % CX;
    return (r < 0) ? r + CX : r;
}

__device__ inline unsigned short pk(float f) {
    unsigned u = __float_as_uint(f);
    u = (u + 0x7FFFu + ((u >> 16) & 1u)) >> 16;
    return (unsigned short)u;
}
__device__ inline float upk(unsigned short h) {
    return __uint_as_float((unsigned)h << 16);
}

// Pass 1: z-interp. T1[x][y][k] = sum_c wz[k][c]*coeff[x][y][zc]. 1,024,000 thr.
__global__ __launch_bounds__(256) void pass_z(const float* __restrict__ coeff,
                                              const float* __restrict__ affine,
                                              const float* __restrict__ fix_aff,
                                              const float* __restrict__ mov_aff,
                                              ushort4* __restrict__ T1) {
    BLOCK_M(M)
    if (M[32] == 0.f) return;
    int tid = blockIdx.x * 256 + threadIdx.x;
    int k = tid % FD;
    int r = tid / FD;          // r = x*80 + y
    float gz = M[10] * (float)k + M[11];
    float fz = floorf(gz);
    float wz[4];
    bspline_w(gz - fz, wz);
    int bz = wrap80((int)fz - 1);
    const float* base = coeff + (size_t)r * (CX * 3);
    float a0 = 0.f, a1 = 0.f, a2 = 0.f;
#pragma unroll
    for (int c = 0; c < 4; ++c) {
        int zc = bz + c; if (zc >= CX) zc -= CX;
        const float* p = base + zc * 3;
        float w = wz[c];
        a0 = fmaf(w, p[0], a0);
        a1 = fmaf(w, p[1], a1);
        a2 = fmaf(w, p[2], a2);
    }
    ushort4 v; v.x = pk(a0); v.y = pk(a1); v.z = pk(a2); v.w = 0;
    T1[tid] = v;
}

// Pass 2: y-interp, coarsened 8 j's/thread, register sliding window.
// T2[x][j][k] = sum_b wy[j][b] * T1[x][yb][k]. 80*20*160 = 256,000 threads.
__global__ __launch_bounds__(256) void pass_y_c(const float* __restrict__ affine,
                                                const float* __restrict__ fix_aff,
                                                const float* __restrict__ mov_aff,
                                                const ushort4* __restrict__ T1,
                                                ushort4* __restrict__ T2) {
    BLOCK_M(M)
    if (M[32] == 0.f) return;
    int tid = blockIdx.x * 256 + threadIdx.x;
    int k = tid % FD;
    int r = tid / FD;
    int jg = r % 20;
    int x = r / 20;
    int j0 = jg * 8;

    const float m5 = M[5], m7 = M[7];
    const ushort4* Tx = T1 + (size_t)x * CX * FD + k;

    float gy = m5 * (float)j0 + m7;
    float fy = floorf(gy);
    int nb = (int)fy - 1;
    float wy[4];
    bspline_w(gy - fy, wy);

    ushort4 w0, w1, w2, w3;
    {
        int y0 = wrap80(nb);
        int y1 = y0 + 1; if (y1 >= CX) y1 -= CX;
        int y2 = y1 + 1; if (y2 >= CX) y2 -= CX;
        int y3 = y2 + 1; if (y3 >= CX) y3 -= CX;
        w0 = Tx[(size_t)y0 * FD];
        w1 = Tx[(size_t)y1 * FD];
        w2 = Tx[(size_t)y2 * FD];
        w3 = Tx[(size_t)y3 * FD];
    }

    ushort4* To = T2 + ((size_t)(x * FD + j0)) * FD + k;
#pragma unroll
    for (int d = 0; d < 8; ++d) {
        if (d > 0) {
            int j = j0 + d;
            gy = m5 * (float)j + m7;
            fy = floorf(gy);
            int b2 = (int)fy - 1;
            if (b2 != nb) {
                w0 = w1; w1 = w2; w2 = w3;
                w3 = Tx[(size_t)wrap80(b2 + 3) * FD];
                nb = b2;
            }
            bspline_w(gy - fy, wy);
        }
        float a0 = wy[0]*upk(w0.x) + wy[1]*upk(w1.x) + wy[2]*upk(w2.x) + wy[3]*upk(w3.x);
        float a1 = wy[0]*upk(w0.y) + wy[1]*upk(w1.y) + wy[2]*upk(w2.y) + wy[3]*upk(w3.y);
        float a2 = wy[0]*upk(w0.z) + wy[1]*upk(w1.z) + wy[2]*upk(w2.z) + wy[3]*upk(w3.z);
        ushort4 v; v.x = pk(a0); v.y = pk(a1); v.z = pk(a2); v.w = 0;
        To[(size_t)d * FD] = v;
    }
}

// Pass 3: x-interp + displacement + ma affine, coarsened 8 i's/thread.
// 20*160*160 = 512,000 threads.
__global__ __launch_bounds__(256) void pass_x_c(const float* __restrict__ coeff,
                                                const float* __restrict__ affine,
                                                const float* __restrict__ fix_aff,
                                                const float* __restrict__ mov_aff,
                                                const ushort4* __restrict__ T2,
                                                float* __restrict__ out) {
    BLOCK_M(M)
    int tid = blockIdx.x * 256 + threadIdx.x;
    int k = tid % FD;
    int r = tid / FD;
    int j = r % FD;
    int ig = r / FD;
    int i0 = ig * 8;

    if (M[32] != 0.f) {
        const float m0 = M[0], m3 = M[3];
        const float gy = M[5] * (float)j + M[7];
        const float gz = M[10] * (float)k + M[11];
        const ushort4* Tjk = T2 + (size_t)j * FD + k;

        float gx = m0 * (float)i0 + m3;
        float fx = floorf(gx);
        int nb = (int)fx - 1;
        float wx[4];
        bspline_w(gx - fx, wx);

        ushort4 w0, w1, w2, w3;
        {
            const size_t S = (size_t)FD * FD;
            int x0 = wrap80(nb);
            int x1 = x0 + 1; if (x1 >= CX) x1 -= CX;
            int x2 = x1 + 1; if (x2 >= CX) x2 -= CX;
            int x3 = x2 + 1; if (x3 >= CX) x3 -= CX;
            w0 = Tjk[(size_t)x0 * S];
            w1 = Tjk[(size_t)x1 * S];
            w2 = Tjk[(size_t)x2 * S];
            w3 = Tjk[(size_t)x3 * S];
        }

        float* po = out + (((size_t)(i0 * FD + j)) * FD + k) * 3;
#pragma unroll
        for (int d = 0; d < 8; ++d) {
            float gxd = gx;
            if (d > 0) {
                int i = i0 + d;
                gxd = m0 * (float)i + m3;
                float fx2 = floorf(gxd);
                int b2 = (int)fx2 - 1;
                if (b2 != nb) {
                    w0 = w1; w1 = w2; w2 = w3;
                    w3 = Tjk[(size_t)wrap80(b2 + 3) * FD * FD];
                    nb = b2;
                }
                bspline_w(gxd - fx2, wx);
            }
            float a0 = wx[0]*upk(w0.x) + wx[1]*upk(w1.x) + wx[2]*upk(w2.x) + wx[3]*upk(w3.x);
            float a1 = wx[0]*upk(w0.y) + wx[1]*upk(w1.y) + wx[2]*upk(w2.y) + wx[3]*upk(w3.y);
            float a2 = wx[0]*upk(w0.z) + wx[1]*upk(w1.z) + wx[2]*upk(w2.z) + wx[3]*upk(w3.z);
            float ux = gxd + a0, uy = gy + a1, uz = gz + a2;
            po[0] = M[16]*ux + M[17]*uy + M[18]*uz + M[19];
            po[1] = M[20]*ux + M[21]*uy + M[22]*uz + M[23];
            po[2] = M[24]*ux + M[25]*uy + M[26]*uz + M[27];
            po += (size_t)FD * FD * 3;   // advance i by 1
        }
    } else {
        // non-separable fallback: direct 64-tap per output
        for (int d = 0; d < 8; ++d) {
            int i = i0 + d;
            float fi = (float)i, fj = (float)j, fk = (float)k;
            float gx = M[0]*fi + M[1]*fj + M[2]*fk  + M[3];
            float gy = M[4]*fi + M[5]*fj + M[6]*fk  + M[7];
            float gz = M[8]*fi + M[9]*fj + M[10]*fk + M[11];
            float fx = floorf(gx), fy = floorf(gy), fz = floorf(gz);
            float wx[4], wy[4], wz[4];
            bspline_w(gx - fx, wx);
            bspline_w(gy - fy, wy);
            bspline_w(gz - fz, wz);
            int bxw = wrap80((int)fx - 1);
            int byw = wrap80((int)fy - 1);
            int bzw = wrap80((int)fz - 1);
            int ox[4], oy[4], oz[4];
            for (int a = 0; a < 4; ++a) {
                int xa = bxw + a; if (xa >= CX) xa -= CX;
                int ya = byw + a; if (ya >= CX) ya -= CX;
                int za = bzw + a; if (za >= CX) za -= CX;
                ox[a] = xa * (CX*CX*3);
                oy[a] = ya * (CX*3);
                oz[a] = za * 3;
            }
            float a0 = 0.f, a1 = 0.f, a2 = 0.f;
            for (int a = 0; a < 4; ++a)
                for (int b = 0; b < 4; ++b)
                    for (int c = 0; c < 4; ++c) {
                        float w = wx[a] * wy[b] * wz[c];
                        const float* p = coeff + (ox[a] + oy[b] + oz[c]);
                        a0 = fmaf(w, p[0], a0);
                        a1 = fmaf(w, p[1], a1);
                        a2 = fmaf(w, p[2], a2);
                    }
            float ux = gx + a0, uy = gy + a1, uz = gz + a2;
            size_t o = ((size_t)(i * FD + j) * FD + k) * 3;
            out[o + 0] = M[16]*ux + M[17]*uy + M[18]*uz + M[19];
            out[o + 1] = M[20]*ux + M[21]*uy + M[22]*uz + M[23];
            out[o + 2] = M[24]*ux + M[25]*uy + M[26]*uz + M[27];
        }
    }
}

// Direct path used when ws can't hold intermediates.
__global__ __launch_bounds__(256) void spline_direct(const float* __restrict__ coeff,
                                                     const float* __restrict__ affine,
                                                     const float* __restrict__ fix_aff,
                                                     const float* __restrict__ mov_aff,
                                                     float* __restrict__ out) {
    BLOCK_M(M)
    int tid = blockIdx.x * 256 + threadIdx.x;
    int k = tid % FD;
    int r = tid / FD;
    int j = r % FD;
    int i = r / FD;
    float fi = (float)i, fj = (float)j, fk = (float)k;
    float gx = M[0]*fi + M[1]*fj + M[2]*fk  + M[3];
    float gy = M[4]*fi + M[5]*fj + M[6]*fk  + M[7];
    float gz = M[8]*fi + M[9]*fj + M[10]*fk + M[11];
    float fx = floorf(gx), fy = floorf(gy), fz = floorf(gz);
    float wx[4], wy[4], wz[4];
    bspline_w(gx - fx, wx);
    bspline_w(gy - fy, wy);
    bspline_w(gz - fz, wz);
    int bxw = wrap80((int)fx - 1);
    int byw = wrap80((int)fy - 1);
    int bzw = wrap80((int)fz - 1);
    int ox[4], oy[4], oz[4];
#pragma unroll
    for (int a = 0; a < 4; ++a) {
        int xa = bxw + a; if (xa >= CX) xa -= CX;
        int ya = byw + a; if (ya >= CX) ya -= CX;
        int za = bzw + a; if (za >= CX) za -= CX;
        ox[a] = xa * (CX*CX*3);
        oy[a] = ya * (CX*3);
        oz[a] = za * 3;
    }
    float a0 = 0.f, a1 = 0.f, a2 = 0.f;
#pragma unroll
    for (int a = 0; a < 4; ++a)
#pragma unroll
        for (int b = 0; b < 4; ++b)
#pragma unroll
            for (int c = 0; c < 4; ++c) {
                float w = wx[a] * wy[b] * wz[c];
                const float* p = coeff + (ox[a] + oy[b] + oz[c]);
                a0 = fmaf(w, p[0], a0);
                a1 = fmaf(w, p[1], a1);
                a2 = fmaf(w, p[2], a2);
            }
    float ux = gx + a0, uy = gy + a1, uz = gz + a2;
    out[tid*3 + 0] = M[16]*ux + M[17]*uy + M[18]*uz + M[19];
    out[tid*3 + 1] = M[20]*ux + M[21]*uy + M[22]*uz + M[23];
    out[tid*3 + 2] = M[24]*ux + M[25]*uy + M[26]*uz + M[27];
}

extern "C" void kernel_launch(void* const* d_in, const int* in_sizes, int n_in,
                              void* d_out, int out_size, void* d_ws, size_t ws_size,
                              hipStream_t stream) {
    const float* coeff   = (const float*)d_in[0];
    const float* affine  = (const float*)d_in[1];
    const float* fix_aff = (const float*)d_in[2];
    const float* mov_aff = (const float*)d_in[3];
    char*  ws   = (char*)d_ws;
    ushort4* T1 = (ushort4*)(ws + 256);                           // 8,192,000 B
    ushort4* T2 = (ushort4*)(ws + 256 + (size_t)CX*CX*FD*8);      // 16,384,000 B
    float* out  = (float*)d_out;

    const size_t need = 256 + (size_t)CX*CX*FD*8 + (size_t)CX*FD*FD*8;

    if (ws_size >= need) {
        pass_z<<<(CX*CX*FD)/256, 256, 0, stream>>>(coeff, affine, fix_aff, mov_aff, T1);
        pass_y_c<<<(CX*20*FD)/256, 256, 0, stream>>>(affine, fix_aff, mov_aff, T1, T2);
        pass_x_c<<<(20*FD*FD)/256, 256, 0, stream>>>(coeff, affine, fix_aff, mov_aff, T2, out);
    } else {
        spline_direct<<<(FD*FD*FD)/256, 256, 0, stream>>>(coeff, affine, fix_aff, mov_aff, out);
    }
}

// Round 12
// 43.433 us; speedup vs baseline: 6.7546x; 2.3018x over previous
//
#include <hip/hip_runtime.h>

// SplineDisp: field[v] = ma @ (g(v) + cubic_bspline_pull(coeff, g(v))),
// g(v) = fa @ v, fa = inv(affine)@fix_affine, ma = inv(mov_affine)@affine.
// Fixed size: coeff [80,80,80,3] f32, out [160,160,160,3] f32.
// R12: R9 champion restored verbatim (setup kernel + 3 passes, bf16x3
// intermediates, register windows; R11's per-block M replication cost 60us —
// reverted). Single change: pass_z coarsened 8x along k with a 12-row
// register shift-queue (36 scalar loads per 8 voxels instead of 96).

#define CX 80
#define FD 160

__device__ inline void inv4(const float* m, float* inv) {
    inv[0]  =  m[5]*m[10]*m[15] - m[5]*m[11]*m[14] - m[9]*m[6]*m[15] + m[9]*m[7]*m[14] + m[13]*m[6]*m[11] - m[13]*m[7]*m[10];
    inv[4]  = -m[4]*m[10]*m[15] + m[4]*m[11]*m[14] + m[8]*m[6]*m[15] - m[8]*m[7]*m[14] - m[12]*m[6]*m[11] + m[12]*m[7]*m[10];
    inv[8]  =  m[4]*m[9]*m[15]  - m[4]*m[11]*m[13] - m[8]*m[5]*m[15] + m[8]*m[7]*m[13] + m[12]*m[5]*m[11] - m[12]*m[7]*m[9];
    inv[12] = -m[4]*m[9]*m[14]  + m[4]*m[10]*m[13] + m[8]*m[5]*m[14] - m[8]*m[6]*m[13] - m[12]*m[5]*m[10] + m[12]*m[6]*m[9];
    inv[1]  = -m[1]*m[10]*m[15] + m[1]*m[11]*m[14] + m[9]*m[2]*m[15] - m[9]*m[3]*m[14] - m[13]*m[2]*m[11] + m[13]*m[3]*m[10];
    inv[5]  =  m[0]*m[10]*m[15] - m[0]*m[11]*m[14] - m[8]*m[2]*m[15] + m[8]*m[3]*m[14] + m[12]*m[2]*m[11] - m[12]*m[3]*m[10];
    inv[9]  = -m[0]*m[9]*m[15]  + m[0]*m[11]*m[13] + m[8]*m[1]*m[15] - m[8]*m[3]*m[13] - m[12]*m[1]*m[11] + m[12]*m[3]*m[9];
    inv[13] =  m[0]*m[9]*m[14]  - m[0]*m[10]*m[13] - m[8]*m[1]*m[14] + m[8]*m[2]*m[13] + m[12]*m[1]*m[10] - m[12]*m[2]*m[9];
    inv[2]  =  m[1]*m[6]*m[15]  - m[1]*m[7]*m[14]  - m[5]*m[2]*m[15] + m[5]*m[3]*m[14] + m[13]*m[2]*m[7]  - m[13]*m[3]*m[6];
    inv[6]  = -m[0]*m[6]*m[15]  + m[0]*m[7]*m[14]  + m[4]*m[2]*m[15] - m[4]*m[3]*m[14] - m[12]*m[2]*m[7]  + m[12]*m[3]*m[6];
    inv[10] =  m[0]*m[5]*m[15]  - m[0]*m[7]*m[13]  - m[4]*m[1]*m[15] + m[4]*m[3]*m[13] + m[12]*m[1]*m[7]  - m[12]*m[3]*m[5];
    inv[14] = -m[0]*m[5]*m[14]  + m[0]*m[6]*m[13]  + m[4]*m[1]*m[14] - m[4]*m[2]*m[13] - m[12]*m[1]*m[6]  + m[12]*m[2]*m[5];
    inv[3]  = -m[1]*m[6]*m[11]  + m[1]*m[7]*m[10]  + m[5]*m[2]*m[11] - m[5]*m[3]*m[10] - m[9]*m[2]*m[7]   + m[9]*m[3]*m[6];
    inv[7]  =  m[0]*m[6]*m[11]  - m[0]*m[7]*m[10]  - m[4]*m[2]*m[11] + m[4]*m[3]*m[10] + m[8]*m[2]*m[7]   - m[8]*m[3]*m[6];
    inv[11] = -m[0]*m[5]*m[11]  + m[0]*m[7]*m[9]   + m[4]*m[1]*m[11] - m[4]*m[3]*m[9]  - m[8]*m[1]*m[7]   + m[8]*m[3]*m[5];
    inv[15] =  m[0]*m[5]*m[10]  - m[0]*m[6]*m[9]   - m[4]*m[1]*m[10] + m[4]*m[2]*m[9]  + m[8]*m[1]*m[6]   - m[8]*m[2]*m[5];
    float det = m[0]*inv[0] + m[1]*inv[4] + m[2]*inv[8] + m[3]*inv[12];
    float rdet = 1.0f / det;
    for (int i = 0; i < 16; ++i) inv[i] *= rdet;
}

// M[0..15]=fa, M[16..31]=ma, M[32]=separable flag (axis-aligned AND 0<diag<=1)
__global__ void setup_mats(const float* __restrict__ affine,
                           const float* __restrict__ fix_aff,
                           const float* __restrict__ mov_aff,
                           float* __restrict__ M) {
    if (threadIdx.x != 0 || blockIdx.x != 0) return;
    float invA[16], invM[16];
    inv4(affine, invA);
    inv4(mov_aff, invM);
    for (int r = 0; r < 4; ++r)
        for (int c = 0; c < 4; ++c) {
            float s = 0.f;
            for (int k = 0; k < 4; ++k) s += invA[r*4+k] * fix_aff[k*4+c];
            M[r*4+c] = s;
        }
    for (int r = 0; r < 4; ++r)
        for (int c = 0; c < 4; ++c) {
            float s = 0.f;
            for (int k = 0; k < 4; ++k) s += invM[r*4+k] * affine[k*4+c];
            M[16 + r*4+c] = s;
        }
    float od = fabsf(M[1]) + fabsf(M[2]) + fabsf(M[4]) + fabsf(M[6]) + fabsf(M[8]) + fabsf(M[9]);
    int ok = (od < 1e-20f)
          && (M[0]  > 0.f) && (M[0]  <= 1.f)
          && (M[5]  > 0.f) && (M[5]  <= 1.f)
          && (M[10] > 0.f) && (M[10] <= 1.f);
    M[32] = ok ? 1.f : 0.f;
}

__device__ inline void bspline_w(float t, float w[4]) {
    float t2 = t * t;
    float t3 = t2 * t;
    const float s = 1.0f / 6.0f;
    w[0] = (1.f - 3.f*t + 3.f*t2 - t3) * s;
    w[1] = (4.f - 6.f*t2 + 3.f*t3) * s;
    w[2] = (1.f + 3.f*t + 3.f*t2 - 3.f*t3) * s;
    w[3] = t3 * s;
}

__device__ inline int wrap80(int v) {
    int r = v % CX;
    return (r < 0) ? r + CX : r;
}

__device__ inline unsigned short pk(float f) {
    unsigned u = __float_as_uint(f);
    u = (u + 0x7FFFu + ((u >> 16) & 1u)) >> 16;
    return (unsigned short)u;
}
__device__ inline float upk(unsigned short h) {
    return __uint_as_float((unsigned)h << 16);
}

struct F3 { float x, y, z; };
__device__ inline F3 ld3(const float* p) { F3 r; r.x = p[0]; r.y = p[1]; r.z = p[2]; return r; }

// Pass 1: z-interp, coarsened 8 k's/thread with 12-row register shift-queue.
// T1[x][y][k] = sum_c wz[k][c]*coeff[x][y][zc]. 80*80*20 = 128,000 threads.
__global__ __launch_bounds__(256) void pass_z_c(const float* __restrict__ coeff,
                                                const float* __restrict__ M,
                                                ushort4* __restrict__ T1) {
    if (M[32] == 0.f) return;
    int tid = blockIdx.x * 256 + threadIdx.x;
    int kg = tid % 20;
    int r  = tid / 20;                  // x*80 + y
    int k0 = kg * 8;

    const float m10 = M[10], m11 = M[11];
    const float* row = coeff + (size_t)r * (CX * 3);

    float gz = m10 * (float)k0 + m11;
    float fz = floorf(gz);
    int nb = (int)fz - 1;
    float wz[4];
    bspline_w(gz - fz, wz);

    // preload the 12 possible tap rows (wrapped), independent scalar loads
    F3 w0, w1, w2, w3, q4, q5, q6, q7, q8, q9, q10, q11;
    {
        int r0 = wrap80(nb);
        int r1 = r0+1;  if (r1 >= CX) r1 -= CX;
        int r2 = r1+1;  if (r2 >= CX) r2 -= CX;
        int r3 = r2+1;  if (r3 >= CX) r3 -= CX;
        int r4 = r3+1;  if (r4 >= CX) r4 -= CX;
        int r5 = r4+1;  if (r5 >= CX) r5 -= CX;
        int r6 = r5+1;  if (r6 >= CX) r6 -= CX;
        int r7 = r6+1;  if (r7 >= CX) r7 -= CX;
        int r8 = r7+1;  if (r8 >= CX) r8 -= CX;
        int r9 = r8+1;  if (r9 >= CX) r9 -= CX;
        int rA = r9+1;  if (rA >= CX) rA -= CX;
        int rB = rA+1;  if (rB >= CX) rB -= CX;
        w0  = ld3(row + r0*3);
        w1  = ld3(row + r1*3);
        w2  = ld3(row + r2*3);
        w3  = ld3(row + r3*3);
        q4  = ld3(row + r4*3);
        q5  = ld3(row + r5*3);
        q6  = ld3(row + r6*3);
        q7  = ld3(row + r7*3);
        q8  = ld3(row + r8*3);
        q9  = ld3(row + r9*3);
        q10 = ld3(row + rA*3);
        q11 = ld3(row + rB*3);
    }

    ushort4* To = T1 + (size_t)r * FD + k0;
#pragma unroll
    for (int d = 0; d < 8; ++d) {
        if (d > 0) {
            int k = k0 + d;
            gz = m10 * (float)k + m11;
            fz = floorf(gz);
            int b2 = (int)fz - 1;
            if (b2 != nb) {                 // advance window: pure register shift
                w0 = w1; w1 = w2; w2 = w3; w3 = q4;
                q4 = q5; q5 = q6; q6 = q7; q7 = q8;
                q8 = q9; q9 = q10; q10 = q11;
                nb = b2;
            }
            bspline_w(gz - fz, wz);
        }
        float a0 = wz[0]*w0.x + wz[1]*w1.x + wz[2]*w2.x + wz[3]*w3.x;
        float a1 = wz[0]*w0.y + wz[1]*w1.y + wz[2]*w2.y + wz[3]*w3.y;
        float a2 = wz[0]*w0.z + wz[1]*w1.z + wz[2]*w2.z + wz[3]*w3.z;
        ushort4 v; v.x = pk(a0); v.y = pk(a1); v.z = pk(a2); v.w = 0;
        To[d] = v;
    }
}

// Pass 2: y-interp, coarsened 8 j's/thread. Preloaded 12-row shift-queue.
// T2[x][j][k] = sum_b wy[j][b] * T1[x][yb][k]. 80*20*160 = 256,000 threads.
__global__ __launch_bounds__(256) void pass_y_c(const float* __restrict__ M,
                                                const ushort4* __restrict__ T1,
                                                ushort4* __restrict__ T2) {
    if (M[32] == 0.f) return;
    int tid = blockIdx.x * 256 + threadIdx.x;
    int k = tid % FD;
    int r = tid / FD;
    int jg = r % 20;
    int x = r / 20;
    int j0 = jg * 8;

    const float m5 = M[5], m7 = M[7];
    const ushort4* Tx = T1 + (size_t)x * CX * FD + k;

    float gy = m5 * (float)j0 + m7;
    float fy = floorf(gy);
    int nb = (int)fy - 1;
    float wy[4];
    bspline_w(gy - fy, wy);

    ushort4 w0, w1, w2, w3, q4, q5, q6, q7, q8, q9, q10, q11;
    {
        int rw = wrap80(nb);
        int r1 = rw+1;  if (r1  >= CX) r1  -= CX;
        int r2 = r1+1;  if (r2  >= CX) r2  -= CX;
        int r3 = r2+1;  if (r3  >= CX) r3  -= CX;
        int r4 = r3+1;  if (r4  >= CX) r4  -= CX;
        int r5 = r4+1;  if (r5  >= CX) r5  -= CX;
        int r6 = r5+1;  if (r6  >= CX) r6  -= CX;
        int r7 = r6+1;  if (r7  >= CX) r7  -= CX;
        int r8 = r7+1;  if (r8  >= CX) r8  -= CX;
        int r9 = r8+1;  if (r9  >= CX) r9  -= CX;
        int rA = r9+1;  if (rA  >= CX) rA  -= CX;
        int rB = rA+1;  if (rB  >= CX) rB  -= CX;
        w0  = Tx[(size_t)rw * FD];
        w1  = Tx[(size_t)r1 * FD];
        w2  = Tx[(size_t)r2 * FD];
        w3  = Tx[(size_t)r3 * FD];
        q4  = Tx[(size_t)r4 * FD];
        q5  = Tx[(size_t)r5 * FD];
        q6  = Tx[(size_t)r6 * FD];
        q7  = Tx[(size_t)r7 * FD];
        q8  = Tx[(size_t)r8 * FD];
        q9  = Tx[(size_t)r9 * FD];
        q10 = Tx[(size_t)rA * FD];
        q11 = Tx[(size_t)rB * FD];
    }

    ushort4* To = T2 + ((size_t)(x * FD + j0)) * FD + k;
#pragma unroll
    for (int d = 0; d < 8; ++d) {
        if (d > 0) {
            int j = j0 + d;
            gy = m5 * (float)j + m7;
            fy = floorf(gy);
            int b2 = (int)fy - 1;
            if (b2 != nb) {
                w0 = w1; w1 = w2; w2 = w3; w3 = q4;
                q4 = q5; q5 = q6; q6 = q7; q7 = q8;
                q8 = q9; q9 = q10; q10 = q11;
                nb = b2;
            }
            bspline_w(gy - fy, wy);
        }
        float a0 = wy[0]*upk(w0.x) + wy[1]*upk(w1.x) + wy[2]*upk(w2.x) + wy[3]*upk(w3.x);
        float a1 = wy[0]*upk(w0.y) + wy[1]*upk(w1.y) + wy[2]*upk(w2.y) + wy[3]*upk(w3.y);
        float a2 = wy[0]*upk(w0.z) + wy[1]*upk(w1.z) + wy[2]*upk(w2.z) + wy[3]*upk(w3.z);
        ushort4 v; v.x = pk(a0); v.y = pk(a1); v.z = pk(a2); v.w = 0;
        To[(size_t)d * FD] = v;
    }
}

// Pass 3: x-interp + displacement + ma affine, coarsened 8 i's/thread.
// Preloaded 12-row shift-queue. 20*160*160 = 512,000 threads.
__global__ __launch_bounds__(256) void pass_x_c(const float* __restrict__ coeff,
                                                const float* __restrict__ M,
                                                const ushort4* __restrict__ T2,
                                                float* __restrict__ out) {
    int tid = blockIdx.x * 256 + threadIdx.x;
    int k = tid % FD;
    int r = tid / FD;
    int j = r % FD;
    int ig = r / FD;
    int i0 = ig * 8;

    if (M[32] != 0.f) {
        const float m0 = M[0], m3 = M[3];
        const float gy = M[5] * (float)j + M[7];
        const float gz = M[10] * (float)k + M[11];
        const ushort4* Tjk = T2 + (size_t)j * FD + k;

        float gx = m0 * (float)i0 + m3;
        float fx = floorf(gx);
        int nb = (int)fx - 1;
        float wx[4];
        bspline_w(gx - fx, wx);

        ushort4 w0, w1, w2, w3, q4, q5, q6, q7, q8, q9, q10, q11;
        {
            const size_t S = (size_t)FD * FD;
            int rw = wrap80(nb);
            int r1 = rw+1;  if (r1  >= CX) r1  -= CX;
            int r2 = r1+1;  if (r2  >= CX) r2  -= CX;
            int r3 = r2+1;  if (r3  >= CX) r3  -= CX;
            int r4 = r3+1;  if (r4  >= CX) r4  -= CX;
            int r5 = r4+1;  if (r5  >= CX) r5  -= CX;
            int r6 = r5+1;  if (r6  >= CX) r6  -= CX;
            int r7 = r6+1;  if (r7  >= CX) r7  -= CX;
            int r8 = r7+1;  if (r8  >= CX) r8  -= CX;
            int r9 = r8+1;  if (r9  >= CX) r9  -= CX;
            int rA = r9+1;  if (rA  >= CX) rA  -= CX;
            int rB = rA+1;  if (rB  >= CX) rB  -= CX;
            w0  = Tjk[(size_t)rw * S];
            w1  = Tjk[(size_t)r1 * S];
            w2  = Tjk[(size_t)r2 * S];
            w3  = Tjk[(size_t)r3 * S];
            q4  = Tjk[(size_t)r4 * S];
            q5  = Tjk[(size_t)r5 * S];
            q6  = Tjk[(size_t)r6 * S];
            q7  = Tjk[(size_t)r7 * S];
            q8  = Tjk[(size_t)r8 * S];
            q9  = Tjk[(size_t)r9 * S];
            q10 = Tjk[(size_t)rA * S];
            q11 = Tjk[(size_t)rB * S];
        }

        float* po = out + (((size_t)(i0 * FD + j)) * FD + k) * 3;
#pragma unroll
        for (int d = 0; d < 8; ++d) {
            float gxd = gx;
            if (d > 0) {
                int i = i0 + d;
                gxd = m0 * (float)i + m3;
                float fx2 = floorf(gxd);
                int b2 = (int)fx2 - 1;
                if (b2 != nb) {
                    w0 = w1; w1 = w2; w2 = w3; w3 = q4;
                    q4 = q5; q5 = q6; q6 = q7; q7 = q8;
                    q8 = q9; q9 = q10; q10 = q11;
                    nb = b2;
                }
                bspline_w(gxd - fx2, wx);
            }
            float a0 = wx[0]*upk(w0.x) + wx[1]*upk(w1.x) + wx[2]*upk(w2.x) + wx[3]*upk(w3.x);
            float a1 = wx[0]*upk(w0.y) + wx[1]*upk(w1.y) + wx[2]*upk(w2.y) + wx[3]*upk(w3.y);
            float a2 = wx[0]*upk(w0.z) + wx[1]*upk(w1.z) + wx[2]*upk(w2.z) + wx[3]*upk(w3.z);
            float ux = gxd + a0, uy = gy + a1, uz = gz + a2;
            po[0] = M[16]*ux + M[17]*uy + M[18]*uz + M[19];
            po[1] = M[20]*ux + M[21]*uy + M[22]*uz + M[23];
            po[2] = M[24]*ux + M[25]*uy + M[26]*uz + M[27];
            po += (size_t)FD * FD * 3;   // advance i by 1
        }
    } else {
        // non-separable fallback: direct 64-tap per output
        for (int d = 0; d < 8; ++d) {
            int i = i0 + d;
            float fi = (float)i, fj = (float)j, fk = (float)k;
            float gx = M[0]*fi + M[1]*fj + M[2]*fk  + M[3];
            float gy = M[4]*fi + M[5]*fj + M[6]*fk  + M[7];
            float gz = M[8]*fi + M[9]*fj + M[10]*fk + M[11];
            float fx = floorf(gx), fy = floorf(gy), fz = floorf(gz);
            float wx[4], wy[4], wz[4];
            bspline_w(gx - fx, wx);
            bspline_w(gy - fy, wy);
            bspline_w(gz - fz, wz);
            int bxw = wrap80((int)fx - 1);
            int byw = wrap80((int)fy - 1);
            int bzw = wrap80((int)fz - 1);
            int ox[4], oy[4], oz[4];
            for (int a = 0; a < 4; ++a) {
                int xa = bxw + a; if (xa >= CX) xa -= CX;
                int ya = byw + a; if (ya >= CX) ya -= CX;
                int za = bzw + a; if (za >= CX) za -= CX;
                ox[a] = xa * (CX*CX*3);
                oy[a] = ya * (CX*3);
                oz[a] = za * 3;
            }
            float a0 = 0.f, a1 = 0.f, a2 = 0.f;
            for (int a = 0; a < 4; ++a)
                for (int b = 0; b < 4; ++b)
                    for (int c = 0; c < 4; ++c) {
                        float w = wx[a] * wy[b] * wz[c];
                        const float* p = coeff + (ox[a] + oy[b] + oz[c]);
                        a0 = fmaf(w, p[0], a0);
                        a1 = fmaf(w, p[1], a1);
                        a2 = fmaf(w, p[2], a2);
                    }
            float ux = gx + a0, uy = gy + a1, uz = gz + a2;
            size_t o = ((size_t)(i * FD + j) * FD + k) * 3;
            out[o + 0] = M[16]*ux + M[17]*uy + M[18]*uz + M[19];
            out[o + 1] = M[20]*ux + M[21]*uy + M[22]*uz + M[23];
            out[o + 2] = M[24]*ux + M[25]*uy + M[26]*uz + M[27];
        }
    }
}

// Direct path used when ws can't hold intermediates.
__global__ __launch_bounds__(256) void spline_direct(const float* __restrict__ coeff,
                                                     const float* __restrict__ M,
                                                     float* __restrict__ out) {
    int tid = blockIdx.x * 256 + threadIdx.x;
    int k = tid % FD;
    int r = tid / FD;
    int j = r % FD;
    int i = r / FD;
    float fi = (float)i, fj = (float)j, fk = (float)k;
    float gx = M[0]*fi + M[1]*fj + M[2]*fk  + M[3];
    float gy = M[4]*fi + M[5]*fj + M[6]*fk  + M[7];
    float gz = M[8]*fi + M[9]*fj + M[10]*fk + M[11];
    float fx = floorf(gx), fy = floorf(gy), fz = floorf(gz);
    float wx[4], wy[4], wz[4];
    bspline_w(gx - fx, wx);
    bspline_w(gy - fy, wy);
    bspline_w(gz - fz, wz);
    int bxw = wrap80((int)fx - 1);
    int byw = wrap80((int)fy - 1);
    int bzw = wrap80((int)fz - 1);
    int ox[4], oy[4], oz[4];
#pragma unroll
    for (int a = 0; a < 4; ++a) {
        int xa = bxw + a; if (xa >= CX) xa -= CX;
        int ya = byw + a; if (ya >= CX) ya -= CX;
        int za = bzw + a; if (za >= CX) za -= CX;
        ox[a] = xa * (CX*CX*3);
        oy[a] = ya * (CX*3);
        oz[a] = za * 3;
    }
    float a0 = 0.f, a1 = 0.f, a2 = 0.f;
#pragma unroll
    for (int a = 0; a < 4; ++a)
#pragma unroll
        for (int b = 0; b < 4; ++b)
#pragma unroll
            for (int c = 0; c < 4; ++c) {
                float w = wx[a] * wy[b] * wz[c];
                const float* p = coeff + (ox[a] + oy[b] + oz[c]);
                a0 = fmaf(w, p[0], a0);
                a1 = fmaf(w, p[1], a1);
                a2 = fmaf(w, p[2], a2);
            }
    float ux = gx + a0, uy = gy + a1, uz = gz + a2;
    out[tid*3 + 0] = M[16]*ux + M[17]*uy + M[18]*uz + M[19];
    out[tid*3 + 1] = M[20]*ux + M[21]*uy + M[22]*uz + M[23];
    out[tid*3 + 2] = M[24]*ux + M[25]*uy + M[26]*uz + M[27];
}

extern "C" void kernel_launch(void* const* d_in, const int* in_sizes, int n_in,
                              void* d_out, int out_size, void* d_ws, size_t ws_size,
                              hipStream_t stream) {
    const float* coeff   = (const float*)d_in[0];
    const float* affine  = (const float*)d_in[1];
    const float* fix_aff = (const float*)d_in[2];
    const float* mov_aff = (const float*)d_in[3];
    float* M    = (float*)d_ws;                                   // 64 floats
    char*  ws   = (char*)d_ws;
    ushort4* T1 = (ushort4*)(ws + 256);                           // 8,192,000 B
    ushort4* T2 = (ushort4*)(ws + 256 + (size_t)CX*CX*FD*8);      // 16,384,000 B
    float* out  = (float*)d_out;

    const size_t need = 256 + (size_t)CX*CX*FD*8 + (size_t)CX*FD*FD*8;

    setup_mats<<<1, 64, 0, stream>>>(affine, fix_aff, mov_aff, M);

    if (ws_size >= need) {
        pass_z_c<<<(CX*CX*20)/256, 256, 0, stream>>>(coeff, M, T1);
        pass_y_c<<<(CX*20*FD)/256, 256, 0, stream>>>(M, T1, T2);
        pass_x_c<<<(20*FD*FD)/256, 256, 0, stream>>>(coeff, M, T2, out);
    } else {
        spline_direct<<<(FD*FD*FD)/256, 256, 0, stream>>>(coeff, M, out);
    }
}

// Round 13
// 39.422 us; speedup vs baseline: 7.4419x; 1.1017x over previous
//
#include <hip/hip_runtime.h>

// SplineDisp: field[v] = ma @ (g(v) + cubic_bspline_pull(coeff, g(v))),
// g(v) = fa @ v, fa = inv(affine)@fix_affine, ma = inv(mov_affine)@affine.
// Fixed size: coeff [80,80,80,3] f32, out [160,160,160,3] f32.
// R13 = R9 champion restored verbatim (best measured: 39.29 us).
// Structure: setup kernel + 3 passes (z: 1 thread/voxel coalesced;
// y/x: 8-outputs/thread register sliding window with 12-row preload),
// bf16x3 packed intermediates in d_ws.
// Measured dead ends: weight tables (R5 -8us), LDS z+y fusion (R6 -8),
// full LDS fusion (R7 -25, 1M bank conflicts), cooperative grid.sync
// (R10 -254: ~100us/barrier on 8 XCDs), per-block M replication (R11 -61),
// pass_z coarsening (R5/R12 -4 each).

#define CX 80
#define FD 160

__device__ inline void inv4(const float* m, float* inv) {
    inv[0]  =  m[5]*m[10]*m[15] - m[5]*m[11]*m[14] - m[9]*m[6]*m[15] + m[9]*m[7]*m[14] + m[13]*m[6]*m[11] - m[13]*m[7]*m[10];
    inv[4]  = -m[4]*m[10]*m[15] + m[4]*m[11]*m[14] + m[8]*m[6]*m[15] - m[8]*m[7]*m[14] - m[12]*m[6]*m[11] + m[12]*m[7]*m[10];
    inv[8]  =  m[4]*m[9]*m[15]  - m[4]*m[11]*m[13] - m[8]*m[5]*m[15] + m[8]*m[7]*m[13] + m[12]*m[5]*m[11] - m[12]*m[7]*m[9];
    inv[12] = -m[4]*m[9]*m[14]  + m[4]*m[10]*m[13] + m[8]*m[5]*m[14] - m[8]*m[6]*m[13] - m[12]*m[5]*m[10] + m[12]*m[6]*m[9];
    inv[1]  = -m[1]*m[10]*m[15] + m[1]*m[11]*m[14] + m[9]*m[2]*m[15] - m[9]*m[3]*m[14] - m[13]*m[2]*m[11] + m[13]*m[3]*m[10];
    inv[5]  =  m[0]*m[10]*m[15] - m[0]*m[11]*m[14] - m[8]*m[2]*m[15] + m[8]*m[3]*m[14] + m[12]*m[2]*m[11] - m[12]*m[3]*m[10];
    inv[9]  = -m[0]*m[9]*m[15]  + m[0]*m[11]*m[13] + m[8]*m[1]*m[15] - m[8]*m[3]*m[13] - m[12]*m[1]*m[11] + m[12]*m[3]*m[9];
    inv[13] =  m[0]*m[9]*m[14]  - m[0]*m[10]*m[13] - m[8]*m[1]*m[14] + m[8]*m[2]*m[13] + m[12]*m[1]*m[10] - m[12]*m[2]*m[9];
    inv[2]  =  m[1]*m[6]*m[15]  - m[1]*m[7]*m[14]  - m[5]*m[2]*m[15] + m[5]*m[3]*m[14] + m[13]*m[2]*m[7]  - m[13]*m[3]*m[6];
    inv[6]  = -m[0]*m[6]*m[15]  + m[0]*m[7]*m[14]  + m[4]*m[2]*m[15] - m[4]*m[3]*m[14] - m[12]*m[2]*m[7]  + m[12]*m[3]*m[6];
    inv[10] =  m[0]*m[5]*m[15]  - m[0]*m[7]*m[13]  - m[4]*m[1]*m[15] + m[4]*m[3]*m[13] + m[12]*m[1]*m[7]  - m[12]*m[3]*m[5];
    inv[14] = -m[0]*m[5]*m[14]  + m[0]*m[6]*m[13]  + m[4]*m[1]*m[14] - m[4]*m[2]*m[13] - m[12]*m[1]*m[6]  + m[12]*m[2]*m[5];
    inv[3]  = -m[1]*m[6]*m[11]  + m[1]*m[7]*m[10]  + m[5]*m[2]*m[11] - m[5]*m[3]*m[10] - m[9]*m[2]*m[7]   + m[9]*m[3]*m[6];
    inv[7]  =  m[0]*m[6]*m[11]  - m[0]*m[7]*m[10]  - m[4]*m[2]*m[11] + m[4]*m[3]*m[10] + m[8]*m[2]*m[7]   - m[8]*m[3]*m[6];
    inv[11] = -m[0]*m[5]*m[11]  + m[0]*m[7]*m[9]   + m[4]*m[1]*m[11] - m[4]*m[3]*m[9]  - m[8]*m[1]*m[7]   + m[8]*m[3]*m[5];
    inv[15] =  m[0]*m[5]*m[10]  - m[0]*m[6]*m[9]   - m[4]*m[1]*m[10] + m[4]*m[2]*m[9]  + m[8]*m[1]*m[6]   - m[8]*m[2]*m[5];
    float det = m[0]*inv[0] + m[1]*inv[4] + m[2]*inv[8] + m[3]*inv[12];
    float rdet = 1.0f / det;
    for (int i = 0; i < 16; ++i) inv[i] *= rdet;
}

// M[0..15]=fa, M[16..31]=ma, M[32]=separable flag (axis-aligned AND 0<diag<=1)
__global__ void setup_mats(const float* __restrict__ affine,
                           const float* __restrict__ fix_aff,
                           const float* __restrict__ mov_aff,
                           float* __restrict__ M) {
    if (threadIdx.x != 0 || blockIdx.x != 0) return;
    float invA[16], invM[16];
    inv4(affine, invA);
    inv4(mov_aff, invM);
    for (int r = 0; r < 4; ++r)
        for (int c = 0; c < 4; ++c) {
            float s = 0.f;
            for (int k = 0; k < 4; ++k) s += invA[r*4+k] * fix_aff[k*4+c];
            M[r*4+c] = s;
        }
    for (int r = 0; r < 4; ++r)
        for (int c = 0; c < 4; ++c) {
            float s = 0.f;
            for (int k = 0; k < 4; ++k) s += invM[r*4+k] * affine[k*4+c];
            M[16 + r*4+c] = s;
        }
    float od = fabsf(M[1]) + fabsf(M[2]) + fabsf(M[4]) + fabsf(M[6]) + fabsf(M[8]) + fabsf(M[9]);
    int ok = (od < 1e-20f)
          && (M[0]  > 0.f) && (M[0]  <= 1.f)
          && (M[5]  > 0.f) && (M[5]  <= 1.f)
          && (M[10] > 0.f) && (M[10] <= 1.f);
    M[32] = ok ? 1.f : 0.f;
}

__device__ inline void bspline_w(float t, float w[4]) {
    float t2 = t * t;
    float t3 = t2 * t;
    const float s = 1.0f / 6.0f;
    w[0] = (1.f - 3.f*t + 3.f*t2 - t3) * s;
    w[1] = (4.f - 6.f*t2 + 3.f*t3) * s;
    w[2] = (1.f + 3.f*t + 3.f*t2 - 3.f*t3) * s;
    w[3] = t3 * s;
}

__device__ inline int wrap80(int v) {
    int r = v % CX;
    return (r < 0) ? r + CX : r;
}

// bf16 pack (RNE) / unpack
__device__ inline unsigned short pk(float f) {
    unsigned u = __float_as_uint(f);
    u = (u + 0x7FFFu + ((u >> 16) & 1u)) >> 16;
    return (unsigned short)u;
}
__device__ inline float upk(unsigned short h) {
    return __uint_as_float((unsigned)h << 16);
}

// Pass 1: z-interp. T1[x][y][k] = sum_c wz[k][c]*coeff[x][y][zc]. 1,024,000 thr.
__global__ __launch_bounds__(256) void pass_z(const float* __restrict__ coeff,
                                              const float* __restrict__ M,
                                              ushort4* __restrict__ T1) {
    if (M[32] == 0.f) return;
    int tid = blockIdx.x * 256 + threadIdx.x;
    int k = tid % FD;
    int r = tid / FD;          // r = x*80 + y
    float gz = M[10] * (float)k + M[11];
    float fz = floorf(gz);
    float wz[4];
    bspline_w(gz - fz, wz);
    int bz = wrap80((int)fz - 1);
    const float* base = coeff + (size_t)r * (CX * 3);
    float a0 = 0.f, a1 = 0.f, a2 = 0.f;
#pragma unroll
    for (int c = 0; c < 4; ++c) {
        int zc = bz + c; if (zc >= CX) zc -= CX;
        const float* p = base + zc * 3;
        float w = wz[c];
        a0 = fmaf(w, p[0], a0);
        a1 = fmaf(w, p[1], a1);
        a2 = fmaf(w, p[2], a2);
    }
    ushort4 v; v.x = pk(a0); v.y = pk(a1); v.z = pk(a2); v.w = 0;
    T1[tid] = v;
}

// Pass 2: y-interp, coarsened 8 j's/thread. Preloaded 12-row shift-queue.
// T2[x][j][k] = sum_b wy[j][b] * T1[x][yb][k]. 80*20*160 = 256,000 threads.
__global__ __launch_bounds__(256) void pass_y_c(const float* __restrict__ M,
                                                const ushort4* __restrict__ T1,
                                                ushort4* __restrict__ T2) {
    if (M[32] == 0.f) return;
    int tid = blockIdx.x * 256 + threadIdx.x;
    int k = tid % FD;
    int r = tid / FD;
    int jg = r % 20;
    int x = r / 20;
    int j0 = jg * 8;

    const float m5 = M[5], m7 = M[7];
    const ushort4* Tx = T1 + (size_t)x * CX * FD + k;

    float gy = m5 * (float)j0 + m7;
    float fy = floorf(gy);
    int nb = (int)fy - 1;
    float wy[4];
    bspline_w(gy - fy, wy);

    // preload rows nb..nb+11 (wrapped): all independent loads, one wait
    ushort4 w0, w1, w2, w3, q4, q5, q6, q7, q8, q9, q10, q11;
    {
        int rw = wrap80(nb);
        int r1 = rw+1;  if (r1  >= CX) r1  -= CX;
        int r2 = r1+1;  if (r2  >= CX) r2  -= CX;
        int r3 = r2+1;  if (r3  >= CX) r3  -= CX;
        int r4 = r3+1;  if (r4  >= CX) r4  -= CX;
        int r5 = r4+1;  if (r5  >= CX) r5  -= CX;
        int r6 = r5+1;  if (r6  >= CX) r6  -= CX;
        int r7 = r6+1;  if (r7  >= CX) r7  -= CX;
        int r8 = r7+1;  if (r8  >= CX) r8  -= CX;
        int r9 = r8+1;  if (r9  >= CX) r9  -= CX;
        int rA = r9+1;  if (rA  >= CX) rA  -= CX;
        int rB = rA+1;  if (rB  >= CX) rB  -= CX;
        w0  = Tx[(size_t)rw * FD];
        w1  = Tx[(size_t)r1 * FD];
        w2  = Tx[(size_t)r2 * FD];
        w3  = Tx[(size_t)r3 * FD];
        q4  = Tx[(size_t)r4 * FD];
        q5  = Tx[(size_t)r5 * FD];
        q6  = Tx[(size_t)r6 * FD];
        q7  = Tx[(size_t)r7 * FD];
        q8  = Tx[(size_t)r8 * FD];
        q9  = Tx[(size_t)r9 * FD];
        q10 = Tx[(size_t)rA * FD];
        q11 = Tx[(size_t)rB * FD];
    }

    ushort4* To = T2 + ((size_t)(x * FD + j0)) * FD + k;
#pragma unroll
    for (int d = 0; d < 8; ++d) {
        if (d > 0) {
            int j = j0 + d;
            gy = m5 * (float)j + m7;
            fy = floorf(gy);
            int b2 = (int)fy - 1;
            if (b2 != nb) {                 // advance window: pure register shift
                w0 = w1; w1 = w2; w2 = w3; w3 = q4;
                q4 = q5; q5 = q6; q6 = q7; q7 = q8;
                q8 = q9; q9 = q10; q10 = q11;
                nb = b2;
            }
            bspline_w(gy - fy, wy);
        }
        float a0 = wy[0]*upk(w0.x) + wy[1]*upk(w1.x) + wy[2]*upk(w2.x) + wy[3]*upk(w3.x);
        float a1 = wy[0]*upk(w0.y) + wy[1]*upk(w1.y) + wy[2]*upk(w2.y) + wy[3]*upk(w3.y);
        float a2 = wy[0]*upk(w0.z) + wy[1]*upk(w1.z) + wy[2]*upk(w2.z) + wy[3]*upk(w3.z);
        ushort4 v; v.x = pk(a0); v.y = pk(a1); v.z = pk(a2); v.w = 0;
        To[(size_t)d * FD] = v;
    }
}

// Pass 3: x-interp + displacement + ma affine, coarsened 8 i's/thread.
// Preloaded 12-row shift-queue. 20*160*160 = 512,000 threads.
__global__ __launch_bounds__(256) void pass_x_c(const float* __restrict__ coeff,
                                                const float* __restrict__ M,
                                                const ushort4* __restrict__ T2,
                                                float* __restrict__ out) {
    int tid = blockIdx.x * 256 + threadIdx.x;
    int k = tid % FD;
    int r = tid / FD;
    int j = r % FD;
    int ig = r / FD;
    int i0 = ig * 8;

    if (M[32] != 0.f) {
        const float m0 = M[0], m3 = M[3];
        const float gy = M[5] * (float)j + M[7];
        const float gz = M[10] * (float)k + M[11];
        const ushort4* Tjk = T2 + (size_t)j * FD + k;

        float gx = m0 * (float)i0 + m3;
        float fx = floorf(gx);
        int nb = (int)fx - 1;
        float wx[4];
        bspline_w(gx - fx, wx);

        ushort4 w0, w1, w2, w3, q4, q5, q6, q7, q8, q9, q10, q11;
        {
            const size_t S = (size_t)FD * FD;
            int rw = wrap80(nb);
            int r1 = rw+1;  if (r1  >= CX) r1  -= CX;
            int r2 = r1+1;  if (r2  >= CX) r2  -= CX;
            int r3 = r2+1;  if (r3  >= CX) r3  -= CX;
            int r4 = r3+1;  if (r4  >= CX) r4  -= CX;
            int r5 = r4+1;  if (r5  >= CX) r5  -= CX;
            int r6 = r5+1;  if (r6  >= CX) r6  -= CX;
            int r7 = r6+1;  if (r7  >= CX) r7  -= CX;
            int r8 = r7+1;  if (r8  >= CX) r8  -= CX;
            int r9 = r8+1;  if (r9  >= CX) r9  -= CX;
            int rA = r9+1;  if (rA  >= CX) rA  -= CX;
            int rB = rA+1;  if (rB  >= CX) rB  -= CX;
            w0  = Tjk[(size_t)rw * S];
            w1  = Tjk[(size_t)r1 * S];
            w2  = Tjk[(size_t)r2 * S];
            w3  = Tjk[(size_t)r3 * S];
            q4  = Tjk[(size_t)r4 * S];
            q5  = Tjk[(size_t)r5 * S];
            q6  = Tjk[(size_t)r6 * S];
            q7  = Tjk[(size_t)r7 * S];
            q8  = Tjk[(size_t)r8 * S];
            q9  = Tjk[(size_t)r9 * S];
            q10 = Tjk[(size_t)rA * S];
            q11 = Tjk[(size_t)rB * S];
        }

        float* po = out + (((size_t)(i0 * FD + j)) * FD + k) * 3;
#pragma unroll
        for (int d = 0; d < 8; ++d) {
            float gxd = gx;
            if (d > 0) {
                int i = i0 + d;
                gxd = m0 * (float)i + m3;
                float fx2 = floorf(gxd);
                int b2 = (int)fx2 - 1;
                if (b2 != nb) {             // advance window: pure register shift
                    w0 = w1; w1 = w2; w2 = w3; w3 = q4;
                    q4 = q5; q5 = q6; q6 = q7; q7 = q8;
                    q8 = q9; q9 = q10; q10 = q11;
                    nb = b2;
                }
                bspline_w(gxd - fx2, wx);
            }
            float a0 = wx[0]*upk(w0.x) + wx[1]*upk(w1.x) + wx[2]*upk(w2.x) + wx[3]*upk(w3.x);
            float a1 = wx[0]*upk(w0.y) + wx[1]*upk(w1.y) + wx[2]*upk(w2.y) + wx[3]*upk(w3.y);
            float a2 = wx[0]*upk(w0.z) + wx[1]*upk(w1.z) + wx[2]*upk(w2.z) + wx[3]*upk(w3.z);
            float ux = gxd + a0, uy = gy + a1, uz = gz + a2;
            po[0] = M[16]*ux + M[17]*uy + M[18]*uz + M[19];
            po[1] = M[20]*ux + M[21]*uy + M[22]*uz + M[23];
            po[2] = M[24]*ux + M[25]*uy + M[26]*uz + M[27];
            po += (size_t)FD * FD * 3;   // advance i by 1
        }
    } else {
        // non-separable fallback: direct 64-tap per output
        for (int d = 0; d < 8; ++d) {
            int i = i0 + d;
            float fi = (float)i, fj = (float)j, fk = (float)k;
            float gx = M[0]*fi + M[1]*fj + M[2]*fk  + M[3];
            float gy = M[4]*fi + M[5]*fj + M[6]*fk  + M[7];
            float gz = M[8]*fi + M[9]*fj + M[10]*fk + M[11];
            float fx = floorf(gx), fy = floorf(gy), fz = floorf(gz);
            float wx[4], wy[4], wz[4];
            bspline_w(gx - fx, wx);
            bspline_w(gy - fy, wy);
            bspline_w(gz - fz, wz);
            int bxw = wrap80((int)fx - 1);
            int byw = wrap80((int)fy - 1);
            int bzw = wrap80((int)fz - 1);
            int ox[4], oy[4], oz[4];
            for (int a = 0; a < 4; ++a) {
                int xa = bxw + a; if (xa >= CX) xa -= CX;
                int ya = byw + a; if (ya >= CX) ya -= CX;
                int za = bzw + a; if (za >= CX) za -= CX;
                ox[a] = xa * (CX*CX*3);
                oy[a] = ya * (CX*3);
                oz[a] = za * 3;
            }
            float a0 = 0.f, a1 = 0.f, a2 = 0.f;
            for (int a = 0; a < 4; ++a)
                for (int b = 0; b < 4; ++b)
                    for (int c = 0; c < 4; ++c) {
                        float w = wx[a] * wy[b] * wz[c];
                        const float* p = coeff + (ox[a] + oy[b] + oz[c]);
                        a0 = fmaf(w, p[0], a0);
                        a1 = fmaf(w, p[1], a1);
                        a2 = fmaf(w, p[2], a2);
                    }
            float ux = gx + a0, uy = gy + a1, uz = gz + a2;
            size_t o = ((size_t)(i * FD + j) * FD + k) * 3;
            out[o + 0] = M[16]*ux + M[17]*uy + M[18]*uz + M[19];
            out[o + 1] = M[20]*ux + M[21]*uy + M[22]*uz + M[23];
            out[o + 2] = M[24]*ux + M[25]*uy + M[26]*uz + M[27];
        }
    }
}

// Direct path used when ws can't hold intermediates.
__global__ __launch_bounds__(256) void spline_direct(const float* __restrict__ coeff,
                                                     const float* __restrict__ M,
                                                     float* __restrict__ out) {
    int tid = blockIdx.x * 256 + threadIdx.x;
    int k = tid % FD;
    int r = tid / FD;
    int j = r % FD;
    int i = r / FD;
    float fi = (float)i, fj = (float)j, fk = (float)k;
    float gx = M[0]*fi + M[1]*fj + M[2]*fk  + M[3];
    float gy = M[4]*fi + M[5]*fj + M[6]*fk  + M[7];
    float gz = M[8]*fi + M[9]*fj + M[10]*fk + M[11];
    float fx = floorf(gx), fy = floorf(gy), fz = floorf(gz);
    float wx[4], wy[4], wz[4];
    bspline_w(gx - fx, wx);
    bspline_w(gy - fy, wy);
    bspline_w(gz - fz, wz);
    int bxw = wrap80((int)fx - 1);
    int byw = wrap80((int)fy - 1);
    int bzw = wrap80((int)fz - 1);
    int ox[4], oy[4], oz[4];
#pragma unroll
    for (int a = 0; a < 4; ++a) {
        int xa = bxw + a; if (xa >= CX) xa -= CX;
        int ya = byw + a; if (ya >= CX) ya -= CX;
        int za = bzw + a; if (za >= CX) za -= CX;
        ox[a] = xa * (CX*CX*3);
        oy[a] = ya * (CX*3);
        oz[a] = za * 3;
    }
    float a0 = 0.f, a1 = 0.f, a2 = 0.f;
#pragma unroll
    for (int a = 0; a < 4; ++a)
#pragma unroll
        for (int b = 0; b < 4; ++b)
#pragma unroll
            for (int c = 0; c < 4; ++c) {
                float w = wx[a] * wy[b] * wz[c];
                const float* p = coeff + (ox[a] + oy[b] + oz[c]);
                a0 = fmaf(w, p[0], a0);
                a1 = fmaf(w, p[1], a1);
                a2 = fmaf(w, p[2], a2);
            }
    float ux = gx + a0, uy = gy + a1, uz = gz + a2;
    out[tid*3 + 0] = M[16]*ux + M[17]*uy + M[18]*uz + M[19];
    out[tid*3 + 1] = M[20]*ux + M[21]*uy + M[22]*uz + M[23];
    out[tid*3 + 2] = M[24]*ux + M[25]*uy + M[26]*uz + M[27];
}

extern "C" void kernel_launch(void* const* d_in, const int* in_sizes, int n_in,
                              void* d_out, int out_size, void* d_ws, size_t ws_size,
                              hipStream_t stream) {
    const float* coeff   = (const float*)d_in[0];
    const float* affine  = (const float*)d_in[1];
    const float* fix_aff = (const float*)d_in[2];
    const float* mov_aff = (const float*)d_in[3];
    float* M    = (float*)d_ws;                                   // 64 floats
    char*  ws   = (char*)d_ws;
    ushort4* T1 = (ushort4*)(ws + 256);                           // 8,192,000 B
    ushort4* T2 = (ushort4*)(ws + 256 + (size_t)CX*CX*FD*8);      // 16,384,000 B
    float* out  = (float*)d_out;

    const size_t need = 256 + (size_t)CX*CX*FD*8 + (size_t)CX*FD*FD*8;

    setup_mats<<<1, 64, 0, stream>>>(affine, fix_aff, mov_aff, M);

    if (ws_size >= need) {
        pass_z<<<(CX*CX*FD)/256, 256, 0, stream>>>(coeff, M, T1);
        pass_y_c<<<(CX*20*FD)/256, 256, 0, stream>>>(M, T1, T2);
        pass_x_c<<<(20*FD*FD)/256, 256, 0, stream>>>(coeff, M, T2, out);
    } else {
        spline_direct<<<(FD*FD*FD)/256, 256, 0, stream>>>(coeff, M, out);
    }
}